// Round 8
// baseline (173.096 us; speedup 1.0000x reference)
//
#include <hip/hip_runtime.h>
#include <hip/hip_fp16.h>
#include <hip/hip_fp8.h>

#define N_NODES 100000
#define E_EDGES 3200000
#define F_IN 11
#define F_H 64
#define F_E 32

#define BSZ 196                          // nodes per bucket
#define NB 511                           // ceil(N_NODES / BSZ) -> ~2 blocks/CU, balanced
#define CAP 7168                         // bucket capacity (mean ~6272, +11 sigma)
#define CHUNK_A 6250                     // 512 * 6250 == E_EDGES exactly
#define NWG_A 512                        // 2 blocks/CU (LDS ~45.6 KB)
#define EPTA 7                           // ceil(CHUNK_A / 1024)

// fixed-point scales for integer LDS accumulation
#define SCALE1 32768.0f                  // layer-1 f16 features (rounding ~1.5e-5/add)
#define SCALE2 512.0f                    // layer-2 fp8 values: EXACT (fp8 * 512 is integer)

typedef __attribute__((ext_vector_type(8))) _Float16 f16x8;
typedef __attribute__((ext_vector_type(4))) _Float16 f16x4;
typedef __attribute__((ext_vector_type(4))) float f32x4;
typedef __attribute__((ext_vector_type(2))) float f32x2;

// ---------------- binA: hist -> wave0 shuffle-scan -> reservation -> LDS stage ->
// coalesced pairs writeout via bucket-id side array (no binary search).
// 512 blocks -> 2 blocks/CU so the serial scatter/writeout phases of one block
// hide under the other block's memory phases.
// (+ fused x -> fp16 conversion prologue; xh consumed only by the NEXT kernel)
__global__ __launch_bounds__(1024) void binA_kernel(const float* __restrict__ x,
                                                    const int* __restrict__ src,
                                                    const int* __restrict__ dst,
                                                    int* __restrict__ cursor,
                                                    unsigned int* __restrict__ pairs,
                                                    _Float16* __restrict__ xh) {
    __shared__ int lh[NB];
    __shared__ int lstart[NB];
    __shared__ int lcur[NB];
    __shared__ int gbase[NB];
    __shared__ unsigned int stage[CHUNK_A];
    __shared__ unsigned short sbuck[CHUNK_A];
    int t = threadIdx.x;

    // fused convert: x [N][11] f32 -> xh [N][12] f16 (zero-padded)
    for (int i = blockIdx.x * 1024 + t; i < N_NODES * 12; i += NWG_A * 1024) {
        int n = i / 12;
        int f = i - n * 12;
        xh[i] = (_Float16)((f < F_IN) ? x[n * F_IN + f] : 0.0f);
    }

    for (int i = t; i < NB; i += 1024) lh[i] = 0;
    __syncthreads();

    int e0 = blockIdx.x * CHUNK_A;
    int e1 = min(e0 + CHUNK_A, E_EDGES);

    unsigned int pv[EPTA];
    int pb[EPTA];
    int cnt = 0;
    for (int i = e0 + t; i < e1; i += 1024) {
        int d = dst[i];
        int b = d / BSZ;                 // constant divide -> magic mul
        int nib = d - b * BSZ;           // 0..195, fits in 8 bits
        pv[cnt] = (unsigned int)src[i] | (((unsigned int)nib) << 17);
        pb[cnt] = b;
        ++cnt;
        atomicAdd(&lh[b], 1);
    }
    __syncthreads();

    // exclusive scan of lh into lstart: wave 0 only, 8 chunks of 64 via shuffles
    if (t < 64) {
        int carry = 0;
        for (int c = 0; c < 8; ++c) {
            int idx = c * 64 + t;
            int hv = (idx < NB) ? lh[idx] : 0;
            int v = hv;
            #pragma unroll
            for (int off = 1; off < 64; off <<= 1) {
                int u = __shfl_up(v, off);
                if (t >= off) v += u;
            }
            if (idx < NB) lstart[idx] = carry + v - hv;
            carry += __shfl(v, 63);
        }
    }
    __syncthreads();

    // per-bucket global reservation + init claim counters
    for (int i = t; i < NB; i += 1024) {
        lcur[i] = lstart[i];
        int c = lh[i];
        if (c > 0) gbase[i] = i * CAP + atomicAdd(&cursor[i], c);
    }
    __syncthreads();

    // scatter into stage, record bucket id per slot
    for (int k = 0; k < cnt; ++k) {
        int b = pb[k];
        int pos = atomicAdd(&lcur[b], 1);
        stage[pos] = pv[k];
        sbuck[pos] = (unsigned short)b;
    }
    __syncthreads();

    // coalesced writeout: consecutive i within a bucket -> consecutive global addrs
    int total = e1 - e0;
    for (int i = t; i < total; i += 1024) {
        int b = sbuck[i];
        pairs[gbase[b] + (i - lstart[b])] = stage[i];
    }
}

// ---------------- K2: fused layer-1 aggregation + dual MFMA projection --------------
// Per bucket (196 nodes): pair-driven INT LDS atomic aggregation (4 lanes/edge,
// 2x unrolled for MLP), then build the A-tile in LDS and run both projections.
__global__ __launch_bounds__(1024, 8) void aggproj_kernel(
        const unsigned int* __restrict__ pairs,
        const int* __restrict__ cursor,
        const _Float16* __restrict__ xh,
        const float* __restrict__ x,
        const float* __restrict__ W1l,
        const float* __restrict__ W1r,
        const float* __restrict__ b1,
        const float* __restrict__ W2l,
        const float* __restrict__ W2r,
        const float* __restrict__ b2,
        float* __restrict__ deg_f,
        unsigned char* __restrict__ p8,
        float* __restrict__ r2) {
    __shared__ int acc[256][13];
    __shared__ __attribute__((aligned(16))) _Float16 hA1[256][32];
    __shared__ __attribute__((aligned(16))) _Float16 hS[256][64];
    __shared__ __attribute__((aligned(16))) _Float16 WB1[64][32];
    __shared__ __attribute__((aligned(16))) _Float16 WB2[64][64];
    int b = blockIdx.x;
    int t = threadIdx.x;

    for (int i = t; i < 256 * 13; i += 1024) ((int*)acc)[i] = 0;
    for (int i = t; i < 64 * 32; i += 1024) {
        int n = i >> 5, k = i & 31;
        float v = 0.0f;
        if (k < F_IN) v = W1l[k * F_H + n];
        else if (k < 2 * F_IN) v = W1r[(k - F_IN) * F_H + n];
        WB1[n][k] = (_Float16)v;
    }
    for (int i = t; i < 64 * 64; i += 1024) {
        int n = i >> 6, k = i & 63;
        float v = (n < F_E) ? W2l[k * F_E + n] : W2r[k * F_E + (n - F_E)];
        WB2[n][k] = (_Float16)v;
    }
    __syncthreads();

    // pair-driven aggregation: 4 lanes/edge, 2 edges/iteration for MLP
    int start = b * CAP;
    int cntAll = cursor[b];
    int q = t & 3;
    for (int i = (t >> 2); i < cntAll; i += 512) {
        unsigned int p0 = pairs[start + i];
        bool h1 = (i + 256) < cntAll;
        unsigned int p1 = h1 ? pairs[start + i + 256] : p0;
        int s0 = p0 & 0x1FFFF, d0 = p0 >> 17;
        int s1 = p1 & 0x1FFFF, d1 = p1 >> 17;
        if (q < 3) {
            f16x4 u0 = *(const f16x4*)(xh + (size_t)s0 * 12 + q * 4);
            f16x4 u1 = *(const f16x4*)(xh + (size_t)s1 * 12 + q * 4);
            int* a0 = &acc[d0][q * 4];
            atomicAdd(&a0[0], __float2int_rn((float)u0[0] * SCALE1));
            atomicAdd(&a0[1], __float2int_rn((float)u0[1] * SCALE1));
            atomicAdd(&a0[2], __float2int_rn((float)u0[2] * SCALE1));
            atomicAdd(&a0[3], __float2int_rn((float)u0[3] * SCALE1));
            if (h1) {
                int* a1 = &acc[d1][q * 4];
                atomicAdd(&a1[0], __float2int_rn((float)u1[0] * SCALE1));
                atomicAdd(&a1[1], __float2int_rn((float)u1[1] * SCALE1));
                atomicAdd(&a1[2], __float2int_rn((float)u1[2] * SCALE1));
                atomicAdd(&a1[3], __float2int_rn((float)u1[3] * SCALE1));
            }
        } else {
            atomicAdd(&acc[d0][12], 1);
            if (h1) atomicAdd(&acc[d1][12], 1);
        }
    }
    __syncthreads();

    // build A-tile: [mean_agg (11) | x (11) | 0-pad], and export degree
    if (t < BSZ) {
        int node = b * BSZ + t;
        if (node < N_NODES) deg_f[node] = (float)acc[t][12];
    }
    for (int i = t; i < 256 * 32; i += 1024) {
        int nl = i >> 5, k = i & 31;
        int node = b * BSZ + nl;
        float v = 0.0f;
        if (nl < BSZ && node < N_NODES) {
            if (k < F_IN) {
                float invd = 1.0f / fmaxf((float)acc[nl][12], 1.0f);
                v = (float)acc[nl][k] * (invd * (1.0f / SCALE1));
            } else if (k < 2 * F_IN) {
                v = x[node * F_IN + (k - F_IN)];
            }
        }
        hA1[nl][k] = (_Float16)v;
    }
    __syncthreads();

    int lane = t & 63;
    int wave = t >> 6;        // 16 waves, wave w owns rows w*16..w*16+15
    int col = lane & 15;
    int quad = lane >> 4;
    int mbase = wave * 16;

    f16x8 afrag = *(const f16x8*)&hA1[mbase + col][quad * 8];
    #pragma unroll
    for (int nt = 0; nt < 4; ++nt) {
        f16x8 bfrag = *(const f16x8*)&WB1[nt * 16 + col][quad * 8];
        float bias = b1[nt * 16 + col];
        f32x4 a = {bias, bias, bias, bias};
        a = __builtin_amdgcn_mfma_f32_16x16x32_f16(afrag, bfrag, a, 0, 0, 0);
        #pragma unroll
        for (int r = 0; r < 4; ++r)
            hS[mbase + quad * 4 + r][nt * 16 + col] = (_Float16)fmaxf(a[r], 0.0f);
    }
    __syncthreads();

    f16x8 a0 = *(const f16x8*)&hS[mbase + col][quad * 8];
    f16x8 a1 = *(const f16x8*)&hS[mbase + col][32 + quad * 8];
    #pragma unroll
    for (int nt = 0; nt < 4; ++nt) {
        f16x8 bf0 = *(const f16x8*)&WB2[nt * 16 + col][quad * 8];
        f16x8 bf1 = *(const f16x8*)&WB2[nt * 16 + col][32 + quad * 8];
        f32x4 a;
        if (nt < 2) {
            a = (f32x4){0.f, 0.f, 0.f, 0.f};
        } else {
            float bb = b2[(nt - 2) * 16 + col];
            a = (f32x4){bb, bb, bb, bb};
        }
        a = __builtin_amdgcn_mfma_f32_16x16x32_f16(a0, bf0, a, 0, 0, 0);
        a = __builtin_amdgcn_mfma_f32_16x16x32_f16(a1, bf1, a, 0, 0, 0);
        #pragma unroll
        for (int r = 0; r < 4; ++r) {
            int row = mbase + quad * 4 + r;
            int node = b * BSZ + row;
            if (row < BSZ && node < N_NODES) {
                if (nt < 2) {
                    __hip_fp8_e4m3 qv((float)a[r]);
                    p8[(size_t)node * F_E + nt * 16 + col] = (unsigned char)qv.__x;
                } else {
                    r2[(size_t)node * F_E + (nt - 2) * 16 + col] = a[r];
                }
            }
        }
    }
}

// decode 4 packed fp8 e4m3 -> 4 floats (hardware cvt on gfx950)
__device__ inline float4 fp8x4_to_f32(unsigned int w) {
#if defined(__gfx950__) || defined(__gfx942__) || defined(__gfx940__) || defined(__gfx941__)
    f32x2 lo = __builtin_amdgcn_cvt_pk_f32_fp8((int)w, false);
    f32x2 hi = __builtin_amdgcn_cvt_pk_f32_fp8((int)w, true);
    return make_float4(lo[0], lo[1], hi[0], hi[1]);
#else
    __hip_fp8_e4m3 a, b, c, d;
    a.__x = (__hip_fp8_storage_t)(w & 0xFF);
    b.__x = (__hip_fp8_storage_t)((w >> 8) & 0xFF);
    c.__x = (__hip_fp8_storage_t)((w >> 16) & 0xFF);
    d.__x = (__hip_fp8_storage_t)((w >> 24) & 0xFF);
    return make_float4((float)a, (float)b, (float)c, (float)d);
#endif
}

// ---------------- K3: pair-driven layer-2 aggregation, INT LDS atomics --------------
// 4 lanes/edge, 4 edges/iteration (all loads issued before any atomic -> 4x MLP);
// TWO accumulator copies (parity cp^u) halve same-address RMW serialization.
// fp8 * 512 is exact; int sum is EXACT.
__global__ __launch_bounds__(1024, 8) void layer2_kernel(const unsigned int* __restrict__ pairs,
                                                         const int* __restrict__ cursor,
                                                         const float* __restrict__ deg_f,
                                                         const unsigned char* __restrict__ p8,
                                                         const float* __restrict__ r2,
                                                         const float* __restrict__ Wc,
                                                         const float* __restrict__ bc,
                                                         float* __restrict__ emb,
                                                         float* __restrict__ logits) {
    __shared__ int acc[2][256][33];
    int b = blockIdx.x;
    int t = threadIdx.x;
    for (int i = t; i < 2 * 256 * 33; i += 1024) ((int*)acc)[i] = 0;
    __syncthreads();

    int start = b * CAP;
    int cntAll = cursor[b];
    int q = t & 3;
    int cp = (t >> 2) & 1;
    for (int i = (t >> 2); i < cntAll; i += 1024) {
        unsigned int pw[4];
        bool hv[4];
        #pragma unroll
        for (int u = 0; u < 4; ++u) {
            int idx = i + u * 256;
            hv[u] = idx < cntAll;
            pw[u] = hv[u] ? pairs[start + idx] : pw[0];
        }
        uint2 w[4];
        #pragma unroll
        for (int u = 0; u < 4; ++u) {
            int s = pw[u] & 0x1FFFF;
            w[u] = *(const uint2*)(p8 + (size_t)s * 32 + q * 8);
        }
        #pragma unroll
        for (int u = 0; u < 4; ++u) {
            if (hv[u]) {
                int d = pw[u] >> 17;
                float4 va = fp8x4_to_f32(w[u].x);
                float4 vb = fp8x4_to_f32(w[u].y);
                int* a = &acc[cp ^ (u & 1)][d][q * 8];
                atomicAdd(&a[0], (int)(va.x * SCALE2));
                atomicAdd(&a[1], (int)(va.y * SCALE2));
                atomicAdd(&a[2], (int)(va.z * SCALE2));
                atomicAdd(&a[3], (int)(va.w * SCALE2));
                atomicAdd(&a[4], (int)(vb.x * SCALE2));
                atomicAdd(&a[5], (int)(vb.y * SCALE2));
                atomicAdd(&a[6], (int)(vb.z * SCALE2));
                atomicAdd(&a[7], (int)(vb.w * SCALE2));
            }
        }
    }
    __syncthreads();

    // merge copy 1 into copy 0
    for (int i = t; i < 256 * 33; i += 1024) ((int*)acc[0])[i] += ((int*)acc[1])[i];
    __syncthreads();

    // epilogue: 4 threads per node, 8 features each
    int n = t >> 2;
    int node = b * BSZ + n;
    if (n < BSZ && node < N_NODES) {
        float sc = (1.0f / SCALE2) / fmaxf(deg_f[node], 1.0f);
        const float* rr = r2 + (size_t)node * F_E + 8 * q;
        float e[8];
        #pragma unroll
        for (int j = 0; j < 8; ++j)
            e[j] = fmaxf((float)acc[0][n][8 * q + j] * sc + rr[j], 0.0f);
        float4* ep = (float4*)(emb + (size_t)node * F_E + 8 * q);
        ep[0] = make_float4(e[0], e[1], e[2], e[3]);
        ep[1] = make_float4(e[4], e[5], e[6], e[7]);
        float c0 = 0.f, c1 = 0.f, c2 = 0.f;
        #pragma unroll
        for (int j = 0; j < 8; ++j) {
            const float* w = Wc + (8 * q + j) * 3;
            c0 += e[j] * w[0];
            c1 += e[j] * w[1];
            c2 += e[j] * w[2];
        }
        c0 += __shfl_xor(c0, 1); c1 += __shfl_xor(c1, 1); c2 += __shfl_xor(c2, 1);
        c0 += __shfl_xor(c0, 2); c1 += __shfl_xor(c1, 2); c2 += __shfl_xor(c2, 2);
        if (q == 0) {
            logits[(size_t)node * 3 + 0] = c0 + bc[0];
            logits[(size_t)node * 3 + 1] = c1 + bc[1];
            logits[(size_t)node * 3 + 2] = c2 + bc[2];
        }
    }
}

extern "C" void kernel_launch(void* const* d_in, const int* in_sizes, int n_in,
                              void* d_out, int out_size, void* d_ws, size_t ws_size,
                              hipStream_t stream) {
    const float* x   = (const float*)d_in[0];
    const int*   ei  = (const int*)d_in[1];
    const float* W1l = (const float*)d_in[2];
    const float* W1r = (const float*)d_in[3];
    const float* b1  = (const float*)d_in[4];
    const float* W2l = (const float*)d_in[5];
    const float* W2r = (const float*)d_in[6];
    const float* b2  = (const float*)d_in[7];
    const float* Wc  = (const float*)d_in[8];
    const float* bc  = (const float*)d_in[9];

    const int* src = ei;
    const int* dst = ei + E_EDGES;

    float* out    = (float*)d_out;
    float* logits = out;
    float* emb    = out + (size_t)N_NODES * 3;

    // ws layout (4B units):
    //   deg_f (N) | cursor(512) | pairs (NB*CAP) | r2 (32N) | p8 (8N)
    //   | xh (6N: [N][12] halves)
    int* ws_i     = (int*)d_ws;
    float* deg_f  = (float*)ws_i;
    int* cursor   = ws_i + N_NODES;
    unsigned int* pairs = (unsigned int*)(cursor + 512);
    int* base2    = (int*)(pairs + (size_t)NB * CAP);
    float* r2     = (float*)base2;                                       // 32N
    unsigned char* p8 = (unsigned char*)(base2 + (size_t)32 * N_NODES);  // 8N units
    _Float16* xh  = (_Float16*)(base2 + (size_t)40 * N_NODES);           // 6N units

    hipMemsetAsync(cursor, 0, 512 * sizeof(int), stream);

    binA_kernel<<<NWG_A, 1024, 0, stream>>>(x, src, dst, cursor, pairs, xh);
    aggproj_kernel<<<NB, 1024, 0, stream>>>(
        pairs, cursor, xh, x, W1l, W1r, b1, W2l, W2r, b2, deg_f, p8, r2);
    layer2_kernel<<<NB, 1024, 0, stream>>>(
        pairs, cursor, deg_f, p8, r2, Wc, bc, emb, logits);
}